// Round 8
// baseline (347.255 us; speedup 1.0000x reference)
//
#include <hip/hip_runtime.h>
#include <hip/hip_bf16.h>

typedef __bf16 bf16;
typedef __bf16 bf16x8 __attribute__((ext_vector_type(8)));
typedef __bf16 bf16x4 __attribute__((ext_vector_type(4)));
typedef short s16x4 __attribute__((ext_vector_type(4)));
typedef float f32x4 __attribute__((ext_vector_type(4)));

static __device__ __forceinline__ f32x4 mfma16(bf16x8 a, bf16x8 b, f32x4 c) {
  return __builtin_amdgcn_mfma_f32_16x16x32_bf16(a, b, c, 0, 0, 0);
}

// 16x16x16 bf16 MFMA (K=16): A/B = 4 bf16 (2 VGPRs). A-frag layout
// A[row=lane&15][k=4*(lane>>4)+j] matches the swapped-QK^T output layout
// S^T[kv=4qq+i][q=lw] exactly -> P feeds PV with ZERO cross-lane shuffles.
static __device__ __forceinline__ f32x4 mfma16k16(bf16x4 a, bf16x4 b, f32x4 c) {
#if __has_builtin(__builtin_amdgcn_mfma_f32_16x16x16bf16_1k)
  return __builtin_amdgcn_mfma_f32_16x16x16bf16_1k(*(s16x4*)&a, *(s16x4*)&b, c, 0, 0, 0);
#else
  asm volatile("v_mfma_f32_16x16x16_bf16 %0, %1, %2, %0" : "+v"(c) : "v"(a), "v"(b));
  return c;
#endif
}

static __device__ __forceinline__ bf16x8 cvt8(const float* p) {
  f32x4 a0 = *(const f32x4*)p;
  f32x4 a1 = *(const f32x4*)(p + 4);
  bf16x8 r;
#pragma unroll
  for (int j = 0; j < 4; ++j) { r[j] = (bf16)a0[j]; r[4 + j] = (bf16)a1[j]; }
  return r;
}

// ---------------------------------------------------------------------------
// prep_wt: write W in MFMA B-fragment order so qkv_gemm's B loads are fully
// coalesced (1024B per wave instruction instead of 16 scattered rows).
// ---------------------------------------------------------------------------
__global__ void prep_wt(const float* __restrict__ Wq, const float* __restrict__ Wk,
                        const float* __restrict__ Wv, bf16* __restrict__ Wf) {
  int k = blockIdx.x;   // 0..255
  int c = threadIdx.x;  // 0..319
  float v;
  if (c < 32)       v = Wq[k * 32 + c];
  else if (c < 64)  v = Wk[k * 32 + (c - 32)];
  else              v = Wv[k * 256 + (c - 64)];
  int t5 = c >> 6, ct = (c >> 4) & 3, lwc = c & 15;
  int kc = k >> 5, qq = (k >> 3) & 3, ke = k & 7;
  Wf[((((t5 * 8 + kc) * 4 + ct) * 64) + qq * 16 + lwc) * 8 + ke] = (bf16)v;
}

// ---------------------------------------------------------------------------
// qkv_gemm: one block per 64-row tile; x A-frags loaded ONCE into registers,
// then looped over all 5 column tiles (Q|K|V). V epilogue via LDS transpose.
// B-frags come from the frag-major Wf layout (coalesced). (unchanged)
// ---------------------------------------------------------------------------
__global__ __launch_bounds__(256) void qkv_gemm(
    const float* __restrict__ x, const bf16* __restrict__ Wf,
    const float* __restrict__ bq, const float* __restrict__ bk,
    const float* __restrict__ bv,
    bf16* __restrict__ Qd, bf16* __restrict__ Kd, bf16* __restrict__ Vt) {
  __shared__ __align__(16) bf16 tile[64 * 72];
  int tid = threadIdx.x;
  int lane = tid & 63, w = tid >> 6;
  int lw = lane & 15, qq = lane >> 4;
  int r0 = blockIdx.x * 64;
  int bb = r0 >> 12, n0 = r0 & 4095;

  const float* arow = x + (size_t)(r0 + 16 * w + lw) * 256;
  bf16x8 a[8];
#pragma unroll
  for (int kc = 0; kc < 8; ++kc) a[kc] = cvt8(arow + kc * 32 + qq * 8);

  for (int c0 = 0; c0 < 320; c0 += 64) {
    int t5 = c0 >> 6;
    f32x4 acc[4] = {};
#pragma unroll
    for (int kc = 0; kc < 8; ++kc)
#pragma unroll
      for (int t = 0; t < 4; ++t) {
        bf16x8 b = *(const bf16x8*)(Wf + ((size_t)(((t5 * 8 + kc) * 4 + t) * 64) + lane) * 8);
        acc[t] = mfma16(a[kc], b, acc[t]);
      }
    // C/D: col = lane&15, row = (lane>>4)*4 + i
    if (c0 == 0) {
#pragma unroll
      for (int t = 0; t < 4; ++t) {
        int c = 16 * t + lw;
        float bias = (c < 32) ? bq[c] : bk[c - 32];
#pragma unroll
        for (int i = 0; i < 4; ++i) {
          int n = n0 + 16 * w + 4 * qq + i;
          bf16 hv = (bf16)(acc[t][i] + bias);
          if (c < 32) Qd[((size_t)(bb << 12) + n) * 32 + c] = hv;
          else        Kd[((size_t)(bb << 12) + n) * 32 + (c - 32)] = hv;
        }
      }
    } else {
#pragma unroll
      for (int t = 0; t < 4; ++t) {
        int cl = 16 * t + lw;
        float bias = bv[c0 - 64 + cl];
#pragma unroll
        for (int i = 0; i < 4; ++i)
          tile[cl * 72 + 16 * w + 4 * qq + i] = (bf16)(acc[t][i] + bias);
      }
      __syncthreads();
      int nl = tid & 63;
#pragma unroll
      for (int it = 0; it < 16; ++it) {
        int cl = 4 * it + w;  // wave-uniform col -> 128B contiguous stores
        Vt[((size_t)bb * 256 + (c0 - 64) + cl) * 4096 + n0 + nl] = tile[cl * 72 + nl];
      }
      __syncthreads();
    }
  }
}

// ---------------------------------------------------------------------------
// flash_attn, BARRIER-FREE / LDS-FREE rewrite (r7 post-mortem: the P LDS
// round-trip + per-tile barrier phase-locked all waves; no pipe >45% busy;
// prefetch/TLP nulls proved the structure itself was the limit).
//
// Swapped QK^T: s = mfma(K_frag, Q_frag) -> lane (qq,lw) holds
// S[kv=4qq+i][q=lw]. After exp + pack to bf16x4 this is EXACTLY the A-frag
// of v_mfma_f32_16x16x16_bf16 (A[row=lw][k=4qq+j]) -> PV consumes P directly
// from registers. No LDS, no __syncthreads, waves fully independent.
//
// Block = 512 threads (8 waves) covering 64 q-rows x 256 ch:
//   wave w: q-group qg=w>>2 (rows r0+32qg..+32, two 16-row subtiles),
//           ch-slice cs=w&3 (ch 64cs..+64, four 16-ch groups).
// QK/exp duplicated x4 across ch-slices (cost: ~128 VALU cyc/wave/32kv of
// v_exp) -- the price of zero cross-wave communication; l is computed
// per-wave, no reduction across waves needed.
// Loop: 128 steps x 32 kv, register double-buffered K/V (literal names).
// ---------------------------------------------------------------------------
__global__ __launch_bounds__(512, 2) void flash_attn(
    const bf16* __restrict__ Qd, const bf16* __restrict__ Kd,
    const bf16* __restrict__ Vt, const float* __restrict__ x,
    const float* __restrict__ gamma, float* __restrict__ out) {
  int tid = threadIdx.x;
  int lane = tid & 63, w = tid >> 6;   // w in 0..7
  int lw = lane & 15, qq = lane >> 4;
  int qg = w >> 2;                      // 0/1: q rows r0+32*qg
  int cs = w & 3;                       // ch slice 64*cs
  int chb = 64 * cs;
  int bb = blockIdx.y;
  int r0 = blockIdx.x * 64;

  const bf16* Qb = Qd + ((size_t)bb << 12) * 32;
  const bf16* Kb = Kd + ((size_t)bb << 12) * 32;
  const bf16* Vb = Vt + (size_t)bb * 256 * 4096;

  // Q fragments for the wave's two 16-row subtiles (held all loop)
  bf16x8 qf0 = *(const bf16x8*)(Qb + (size_t)(r0 + 32 * qg + lw) * 32 + qq * 8);
  bf16x8 qf1 = *(const bf16x8*)(Qb + (size_t)(r0 + 32 * qg + 16 + lw) * 32 + qq * 8);

  f32x4 o[2][4] = {};                   // [q-subtile][16-ch group]
  float l0 = 0.f, l1 = 0.f;             // per-lane l partial for q=lw

  bf16x8 kA[2], kB[2];                  // K[16 kv][32 d] frags, 2 kv-tiles
  bf16x4 vA[4][2], vB[4][2];            // V^T[ch=chb+16t+lw][kv=4qq..+3]

  // ---- prologue: load buffers for step 0 ----
#pragma unroll
  for (int u = 0; u < 2; ++u)
    kA[u] = *(const bf16x8*)(Kb + (size_t)(16 * u + lw) * 32 + qq * 8);
#pragma unroll
  for (int t = 0; t < 4; ++t)
#pragma unroll
    for (int u = 0; u < 2; ++u)
      vA[t][u] = *(const bf16x4*)(Vb + (size_t)(chb + 16 * t + lw) * 4096 + 16 * u + 4 * qq);

  // STEP: prefetch next (N0N) into KN/VN, compute current from KC/VC.
#define FA_STEP(N0N, KC, KN, VC, VN)                                               \
  {                                                                                \
    _Pragma("unroll") for (int u = 0; u < 2; ++u)                                  \
      KN[u] = *(const bf16x8*)(Kb + (size_t)((N0N) + 16 * u + lw) * 32 + qq * 8);  \
    _Pragma("unroll") for (int t = 0; t < 4; ++t)                                  \
      _Pragma("unroll") for (int u = 0; u < 2; ++u)                                \
        VN[t][u] = *(const bf16x4*)(Vb + (size_t)(chb + 16 * t + lw) * 4096 + (N0N) + 16 * u + 4 * qq); \
    _Pragma("unroll") for (int u = 0; u < 2; ++u) {                                \
      f32x4 z = {};                                                                \
      f32x4 s0 = mfma16(KC[u], qf0, z);                                            \
      f32x4 s1 = mfma16(KC[u], qf1, z);                                            \
      bf16x4 pa0, pa1;                                                             \
      _Pragma("unroll") for (int i = 0; i < 4; ++i) {                              \
        float p0 = __expf(s0[i]); l0 += p0; pa0[i] = (bf16)p0;                     \
        float p1 = __expf(s1[i]); l1 += p1; pa1[i] = (bf16)p1;                     \
      }                                                                            \
      _Pragma("unroll") for (int t = 0; t < 4; ++t) {                              \
        o[0][t] = mfma16k16(pa0, VC[t][u], o[0][t]);                               \
        o[1][t] = mfma16k16(pa1, VC[t][u], o[1][t]);                               \
      }                                                                            \
    }                                                                              \
  }

  for (int j2 = 0; j2 < 64; ++j2) {
    int a0 = j2 * 64;
    FA_STEP(a0 + 32, kA, kB, vA, vB)
    FA_STEP((a0 + 64) & 4095, kB, kA, vB, vA)
  }
#undef FA_STEP

  // ---- l finalize: reduce across qq groups, then transpose to o layout ----
  l0 += __shfl_xor(l0, 16); l0 += __shfl_xor(l0, 32);
  l1 += __shfl_xor(l1, 16); l1 += __shfl_xor(l1, 32);
  // lane (qq,lw) needs l for q-row 4qq+i; lanes 0..15 hold l[q=lane]
  float li0[4], li1[4];
#pragma unroll
  for (int i = 0; i < 4; ++i) {
    li0[i] = __shfl(l0, 4 * qq + i);
    li1[i] = __shfl(l1, 4 * qq + i);
  }

  float g = gamma[0];
#pragma unroll
  for (int i = 0; i < 4; ++i) {
    float r0v = 1.f / li0[i];
    float r1v = 1.f / li1[i];
    int row0 = r0 + 32 * qg + 4 * qq + i;
    int row1 = row0 + 16;
    size_t b0 = (((size_t)bb << 12) + row0) * 256 + chb;
    size_t b1 = (((size_t)bb << 12) + row1) * 256 + chb;
#pragma unroll
    for (int t = 0; t < 4; ++t) {
      out[b0 + 16 * t + lw] = g * (o[0][t][i] * r0v) + x[b0 + 16 * t + lw];
      out[b1 + 16 * t + lw] = g * (o[1][t][i] * r1v) + x[b1 + 16 * t + lw];
    }
  }
}

extern "C" void kernel_launch(void* const* d_in, const int* in_sizes, int n_in,
                              void* d_out, int out_size, void* d_ws, size_t ws_size,
                              hipStream_t stream) {
  const float* x     = (const float*)d_in[0];
  const float* Wq    = (const float*)d_in[1];
  const float* bq    = (const float*)d_in[2];
  const float* Wk    = (const float*)d_in[3];
  const float* bk    = (const float*)d_in[4];
  const float* Wv    = (const float*)d_in[5];
  const float* bv    = (const float*)d_in[6];
  const float* gamma = (const float*)d_in[7];
  float* out = (float*)d_out;

  const size_t WT_E = 320 * 256;
  const size_t QK_E = (size_t)4096 * 32;
  const size_t VT_E = (size_t)256 * 4096;
  size_t full_bytes = (WT_E + 4 * 2 * QK_E + 4 * VT_E) * sizeof(bf16);

  bf16* Wf = (bf16*)d_ws;
  prep_wt<<<dim3(256), dim3(320), 0, stream>>>(Wq, Wk, Wv, Wf);

  if (ws_size >= full_bytes) {
    bf16* Qd = Wf + WT_E;
    bf16* Kd = Qd + 4 * QK_E;
    bf16* Vt = Kd + 4 * QK_E;
    qkv_gemm<<<dim3(256), dim3(256), 0, stream>>>(x, Wf, bq, bk, bv, Qd, Kd, Vt);
    flash_attn<<<dim3(64, 4), dim3(512), 0, stream>>>(Qd, Kd, Vt, x, gamma, out);
  } else {
    bf16* Qd = Wf + WT_E;
    bf16* Kd = Qd + QK_E;
    bf16* Vt = Kd + QK_E;
    for (int b = 0; b < 4; ++b) {
      const float* xb = x + (size_t)b * 4096 * 256;
      float* outb = out + (size_t)b * 4096 * 256;
      qkv_gemm<<<dim3(64), dim3(256), 0, stream>>>(xb, Wf, bq, bk, bv, Qd, Kd, Vt);
      flash_attn<<<dim3(64, 1), dim3(512), 0, stream>>>(Qd, Kd, Vt, xb, gamma, outb);
    }
  }
}

// Round 9
// 170.432 us; speedup vs baseline: 2.0375x; 2.0375x over previous
//
#include <hip/hip_runtime.h>
#include <hip/hip_bf16.h>

typedef __bf16 bf16;
typedef __bf16 bf16x8 __attribute__((ext_vector_type(8)));
typedef float f32x4 __attribute__((ext_vector_type(4)));

static __device__ __forceinline__ f32x4 mfma16(bf16x8 a, bf16x8 b, f32x4 c) {
  return __builtin_amdgcn_mfma_f32_16x16x32_bf16(a, b, c, 0, 0, 0);
}

// No-drain workgroup barrier (r5: neutral vs __syncthreads, kept).
static __device__ __forceinline__ void wg_barrier() {
  asm volatile("s_waitcnt lgkmcnt(0)" ::: "memory");
  __builtin_amdgcn_s_barrier();
  asm volatile("" ::: "memory");
}

static __device__ __forceinline__ bf16x8 cvt8(const float* p) {
  f32x4 a0 = *(const f32x4*)p;
  f32x4 a1 = *(const f32x4*)(p + 4);
  bf16x8 r;
#pragma unroll
  for (int j = 0; j < 4; ++j) { r[j] = (bf16)a0[j]; r[4 + j] = (bf16)a1[j]; }
  return r;
}

// ---------------------------------------------------------------------------
// prep_wt: write W in MFMA B-fragment order (unchanged).
// ---------------------------------------------------------------------------
__global__ void prep_wt(const float* __restrict__ Wq, const float* __restrict__ Wk,
                        const float* __restrict__ Wv, bf16* __restrict__ Wf) {
  int k = blockIdx.x;   // 0..255
  int c = threadIdx.x;  // 0..319
  float v;
  if (c < 32)       v = Wq[k * 32 + c];
  else if (c < 64)  v = Wk[k * 32 + (c - 32)];
  else              v = Wv[k * 256 + (c - 64)];
  int t5 = c >> 6, ct = (c >> 4) & 3, lwc = c & 15;
  int kc = k >> 5, qq = (k >> 3) & 3, ke = k & 7;
  Wf[((((t5 * 8 + kc) * 4 + ct) * 64) + qq * 16 + lwc) * 8 + ke] = (bf16)v;
}

// ---------------------------------------------------------------------------
// qkv_gemm v2 — occupancy fix (r8 post-mortem: v1 ran 256 blocks x 4 waves =
// 1 wave/SIMD, zero latency hiding; the constant ~80us non-flash gap is its
// likely cost). Now: 32-row tiles, 512 threads (8 waves = 2 row-groups x
// 4 col-groups), grid 512 -> 2 blocks/CU -> 4 waves/SIMD.
// Wave w: rows 16*(w&1)..+16 of the 32-row tile, cols 16*(w>>2? no: w>>1)
// within each 64-col c0 tile. Same Wf fragment layout (t index = cg).
// ---------------------------------------------------------------------------
__global__ __launch_bounds__(512, 4) void qkv_gemm(
    const float* __restrict__ x, const bf16* __restrict__ Wf,
    const float* __restrict__ bq, const float* __restrict__ bk,
    const float* __restrict__ bv,
    bf16* __restrict__ Qd, bf16* __restrict__ Kd, bf16* __restrict__ Vt) {
  __shared__ __align__(16) bf16 tile[64 * 72];
  int tid = threadIdx.x;
  int lane = tid & 63, w = tid >> 6;   // w in 0..7
  int lw = lane & 15, qq = lane >> 4;
  int rg = w & 1, cg = w >> 1;         // rows 16*rg, col-group 16*cg
  int r0 = blockIdx.x * 32;
  int bb = r0 >> 12, n0 = r0 & 4095;

  const float* arow = x + (size_t)(r0 + 16 * rg + lw) * 256;
  bf16x8 a[8];
#pragma unroll
  for (int kc = 0; kc < 8; ++kc) a[kc] = cvt8(arow + kc * 32 + qq * 8);

  for (int c0 = 0; c0 < 320; c0 += 64) {
    int t5 = c0 >> 6;
    f32x4 acc = {};
#pragma unroll
    for (int kc = 0; kc < 8; ++kc) {
      bf16x8 b = *(const bf16x8*)(Wf + ((size_t)(((t5 * 8 + kc) * 4 + cg) * 64) + lane) * 8);
      acc = mfma16(a[kc], b, acc);
    }
    // C/D: col = lane&15, row = (lane>>4)*4 + i
    if (c0 == 0) {
      int c = 16 * cg + lw;
      float bias = (c < 32) ? bq[c] : bk[c - 32];
#pragma unroll
      for (int i = 0; i < 4; ++i) {
        int n = n0 + 16 * rg + 4 * qq + i;
        bf16 hv = (bf16)(acc[i] + bias);
        if (c < 32) Qd[((size_t)(bb << 12) + n) * 32 + c] = hv;
        else        Kd[((size_t)(bb << 12) + n) * 32 + (c - 32)] = hv;
      }
    } else {
      int cl = 16 * cg + lw;
      float bias = bv[c0 - 64 + cl];
#pragma unroll
      for (int i = 0; i < 4; ++i)
        tile[cl * 72 + 16 * rg + 4 * qq + i] = (bf16)(acc[i] + bias);
      __syncthreads();
#pragma unroll
      for (int it = 0; it < 4; ++it) {
        int ch = 16 * it + (tid >> 5);   // 0..63
        int n  = tid & 31;               // 32 consecutive n -> 64B contiguous
        Vt[((size_t)bb * 256 + (c0 - 64) + ch) * 4096 + n0 + n] = tile[ch * 72 + n];
      }
      __syncthreads();
    }
  }
}

// ---------------------------------------------------------------------------
// flash_attn: r5-exact (proven 85us). 64-row q-tiles, 512 threads (8 waves),
// grid (64,B), disjoint 32-ch per wave (traffic-optimal per r8 accounting),
// P via double-buffered LDS, one wg_barrier per tile, no setprio.
// ---------------------------------------------------------------------------
__global__ __launch_bounds__(512, 2) void flash_attn(
    const bf16* __restrict__ Qd, const bf16* __restrict__ Kd,
    const bf16* __restrict__ Vt, const float* __restrict__ x,
    const float* __restrict__ gamma, float* __restrict__ out) {
  __shared__ __align__(16) bf16 Pl[2][64 * 72];
  __shared__ __align__(16) float lsum2[2][64];

  int tid = threadIdx.x;
  int lane = tid & 63, w = tid >> 6;
  int lw = lane & 15, qq = lane >> 4;
  int wr = w & 3, wc = w >> 2, chb = 32 * w;
  int bb = blockIdx.y;
  int r0 = blockIdx.x * 64;

  const bf16* Qb = Qd + ((size_t)bb << 12) * 32;
  const bf16* Kb = Kd + ((size_t)bb << 12) * 32;
  const bf16* Vb = Vt + (size_t)bb * 256 * 4096;

  bf16x8 qf = *(const bf16x8*)(Qb + (size_t)(r0 + 16 * wr + lw) * 32 + qq * 8);

  f32x4 o[4][2] = {};
  float l_part[4] = {};
  bf16x8 kbuf0[2], kbuf1[2], vbuf0[4], vbuf1[4];

  // ---- prologue: S(0) -> Pl[0]; prefetch K(1), V(0) ----
#pragma unroll
  for (int t = 0; t < 2; ++t)
    kbuf0[t] = *(const bf16x8*)(Kb + (size_t)(32 * wc + 16 * t + lw) * 32 + qq * 8);
  {
    f32x4 s[2];
#pragma unroll
    for (int t = 0; t < 2; ++t) { f32x4 z = {}; s[t] = mfma16(qf, kbuf0[t], z); }
#pragma unroll
    for (int t = 0; t < 2; ++t)
#pragma unroll
      for (int i = 0; i < 4; ++i) {
        float p = __expf(s[t][i]);
        l_part[i] += p;
        Pl[0][(16 * wr + 4 * qq + i) * 72 + 32 * wc + 16 * t + lw] = (bf16)p;
      }
  }
#pragma unroll
  for (int t = 0; t < 2; ++t)
    kbuf1[t] = *(const bf16x8*)(Kb + (size_t)(64 + 32 * wc + 16 * t + lw) * 32 + qq * 8);
#pragma unroll
  for (int t = 0; t < 2; ++t)
#pragma unroll
    for (int kc = 0; kc < 2; ++kc)
      vbuf0[t * 2 + kc] = *(const bf16x8*)(Vb + (size_t)(chb + 16 * t + lw) * 4096 + kc * 32 + qq * 8);
  wg_barrier();

  // BODY(j, PCUR, PNXT, KN, KC, VC, VN): literal register-buffer names.
#define FA_BODY(J, PCUR, PNXT, KN, KC, VC, VN)                                     \
  {                                                                                \
    const int j = (J);                                                             \
    int n1 = ((j + 1) & 63) * 64, n2 = ((j + 2) & 63) * 64;                        \
    bf16x8 af[4][2];                                                               \
    _Pragma("unroll") for (int m = 0; m < 4; ++m)                                  \
      _Pragma("unroll") for (int kc = 0; kc < 2; ++kc)                             \
        af[m][kc] = *(const bf16x8*)&Pl[PCUR][(16 * m + lw) * 72 + kc * 32 + qq * 8]; \
    if (j < 63) {                                                                  \
      f32x4 s[2];                                                                  \
      _Pragma("unroll") for (int t = 0; t < 2; ++t) {                              \
        f32x4 z = {};                                                              \
        s[t] = mfma16(qf, KN[t], z);                                               \
      }                                                                            \
      _Pragma("unroll") for (int t = 0; t < 2; ++t)                                \
        _Pragma("unroll") for (int i = 0; i < 4; ++i) {                            \
          float p = __expf(s[t][i]);                                               \
          l_part[i] += p;                                                          \
          Pl[PNXT][(16 * wr + 4 * qq + i) * 72 + 32 * wc + 16 * t + lw] = (bf16)p; \
        }                                                                          \
      _Pragma("unroll") for (int t = 0; t < 2; ++t)                                \
        KC[t] = *(const bf16x8*)(Kb + (size_t)(n2 + 32 * wc + 16 * t + lw) * 32 + qq * 8); \
    }                                                                              \
    _Pragma("unroll") for (int t = 0; t < 2; ++t)                                  \
      _Pragma("unroll") for (int kc = 0; kc < 2; ++kc)                             \
        VN[t * 2 + kc] = *(const bf16x8*)(Vb + (size_t)(chb + 16 * t + lw) * 4096 + n1 + kc * 32 + qq * 8); \
    _Pragma("unroll") for (int kc = 0; kc < 2; ++kc)                               \
      _Pragma("unroll") for (int t = 0; t < 2; ++t)                                \
        _Pragma("unroll") for (int m = 0; m < 4; ++m)                              \
          o[m][t] = mfma16(af[m][kc], VC[t * 2 + kc], o[m][t]);                    \
    wg_barrier();                                                                  \
  }

  for (int jj = 0; jj < 32; ++jj) {
    FA_BODY(2 * jj,     0, 1, kbuf1, kbuf0, vbuf0, vbuf1)
    FA_BODY(2 * jj + 1, 1, 0, kbuf0, kbuf1, vbuf1, vbuf0)
  }
#undef FA_BODY

  // ---- l reduction ----
#pragma unroll
  for (int i = 0; i < 4; ++i) {
    float v = l_part[i];
    v += __shfl_xor(v, 1);
    v += __shfl_xor(v, 2);
    v += __shfl_xor(v, 4);
    v += __shfl_xor(v, 8);
    if (lw == 0) lsum2[wc][16 * wr + 4 * qq + i] = v;
  }
  __syncthreads();

  float g = gamma[0];
#pragma unroll
  for (int m = 0; m < 4; ++m) {
    f32x4 la = *(const f32x4*)&lsum2[0][16 * m + 4 * qq];
    f32x4 lb = *(const f32x4*)&lsum2[1][16 * m + 4 * qq];
#pragma unroll
    for (int i = 0; i < 4; ++i) {
      float rinv = 1.f / (la[i] + lb[i]);
      int row = r0 + 16 * m + 4 * qq + i;
      size_t base = (((size_t)bb << 12) + row) * 256 + chb;
#pragma unroll
      for (int t = 0; t < 2; ++t)
        out[base + 16 * t + lw] = g * (o[m][t][i] * rinv) + x[base + 16 * t + lw];
    }
  }
}

extern "C" void kernel_launch(void* const* d_in, const int* in_sizes, int n_in,
                              void* d_out, int out_size, void* d_ws, size_t ws_size,
                              hipStream_t stream) {
  const float* x     = (const float*)d_in[0];
  const float* Wq    = (const float*)d_in[1];
  const float* bq    = (const float*)d_in[2];
  const float* Wk    = (const float*)d_in[3];
  const float* bk    = (const float*)d_in[4];
  const float* Wv    = (const float*)d_in[5];
  const float* bv    = (const float*)d_in[6];
  const float* gamma = (const float*)d_in[7];
  float* out = (float*)d_out;

  const size_t WT_E = 320 * 256;
  const size_t QK_E = (size_t)4096 * 32;
  const size_t VT_E = (size_t)256 * 4096;
  size_t full_bytes = (WT_E + 4 * 2 * QK_E + 4 * VT_E) * sizeof(bf16);

  bf16* Wf = (bf16*)d_ws;
  prep_wt<<<dim3(256), dim3(320), 0, stream>>>(Wq, Wk, Wv, Wf);

  if (ws_size >= full_bytes) {
    bf16* Qd = Wf + WT_E;
    bf16* Kd = Qd + 4 * QK_E;
    bf16* Vt = Kd + 4 * QK_E;
    qkv_gemm<<<dim3(512), dim3(512), 0, stream>>>(x, Wf, bq, bk, bv, Qd, Kd, Vt);
    flash_attn<<<dim3(64, 4), dim3(512), 0, stream>>>(Qd, Kd, Vt, x, gamma, out);
  } else {
    bf16* Qd = Wf + WT_E;
    bf16* Kd = Qd + QK_E;
    bf16* Vt = Kd + QK_E;
    for (int b = 0; b < 4; ++b) {
      const float* xb = x + (size_t)b * 4096 * 256;
      float* outb = out + (size_t)b * 4096 * 256;
      qkv_gemm<<<dim3(128), dim3(512), 0, stream>>>(xb, Wf, bq, bk, bv, Qd, Kd, Vt);
      flash_attn<<<dim3(64, 1), dim3(512), 0, stream>>>(Qd, Kd, Vt, xb, gamma, outb);
    }
  }
}